// Round 4
// baseline (256121.875 us; speedup 1.0000x reference)
//
#include <hip/hip_runtime.h>
#include <hip/hip_bf16.h>

// Problem constants
#define BB   128   // batch
#define TT   400   // encoder length
#define KVD  128   // key/value dim (= layer2 hidden)
#define VV   1024  // vocab
#define EE   256   // embed dim
#define HH   512   // layer1 hidden
#define LL   300   // decode length
#define D1   896   // E + KV + H (layer1 input incl. recurrent)
#define NBLK 256
#define NTHR 256

// workspace layout (float units)
#define XT_SZ   (D1 * BB)             // 114688 floats per parity buffer
#define XT_OFF  0                     // 2 buffers
#define H2_SZ   (KVD * BB)            // 16384 floats per parity buffer
#define H2_OFF  (2 * XT_SZ)           // 229376
#define FLAG_OFF (H2_OFF + 2 * H2_SZ) // unsigned flags[256] + gen + isf
#define PLOT_OFF (BB * LL * VV)       // 39321600 (attn_plot offset in out)

typedef unsigned short ushort_t;

__device__ __forceinline__ float bf2f(ushort_t u) {
  return __uint_as_float(((unsigned)u) << 16);
}
__device__ __forceinline__ float lo16(unsigned u) { return __uint_as_float(u << 16); }
__device__ __forceinline__ float hi16(unsigned u) { return __uint_as_float(u & 0xffff0000u); }
__device__ __forceinline__ ushort_t f2bf(float f) {
  unsigned u = __float_as_uint(f);
  return (ushort_t)((u + 0x7FFFu + ((u >> 16) & 1u)) >> 16);  // RNE
}
__device__ __forceinline__ float sigm(float x) { return 1.0f / (1.0f + expf(-x)); }

// dtype-agnostic element load/store (isf: buffer is fp32, else bf16)
__device__ __forceinline__ float ldx(const void* p, size_t i, bool isf) {
  return isf ? ((const float*)p)[i] : bf2f(((const ushort_t*)p)[i]);
}
__device__ __forceinline__ void stx(void* p, size_t i, float v, bool isf) {
  if (isf) ((float*)p)[i] = v; else ((ushort_t*)p)[i] = f2bf(v);
}

// ---------------------------------------------------------------------------
// probe: decide whether float tensors are fp32 or bf16.
// ---------------------------------------------------------------------------
__global__ void probe_kernel(const void* __restrict__ w_out, float* __restrict__ ws) {
  if (blockIdx.x == 0 && threadIdx.x == 0) {
    const ushort_t* p = (const ushort_t*)w_out;
    int bad = 0;
    for (int i = 0; i < 512; ++i) {
      float v = bf2f(p[i]);
      if (!(fabsf(v) < 0.5f)) bad++;   // counts NaN/inf too
    }
    unsigned* flags = (unsigned*)(ws + FLAG_OFF);
    flags[NBLK + 1] = (bad > 0) ? 1u : 0u;
  }
}

// ---------------------------------------------------------------------------
// init: zero parity-0 state, seed <sos> embedding, zero barrier flags
// ---------------------------------------------------------------------------
__global__ void __launch_bounds__(NTHR) init_kernel(const void* __restrict__ emb,
                                                    float* __restrict__ ws) {
  unsigned* flags = (unsigned*)(ws + FLAG_OFF);
  const bool isf = flags[NBLK + 1] != 0;
  int idx = blockIdx.x * NTHR + threadIdx.x;
  if (idx < XT_SZ) {
    int k = idx >> 7;  // row of xT (col = idx & 127)
    ws[XT_OFF + idx] = (k < EE) ? ldx(emb, EE + k, isf) : 0.0f;  // SOS token = 1
  }
  int j = idx - XT_SZ;
  if (j >= 0 && j < H2_SZ) ws[H2_OFF + j] = 0.0f;
  int f = idx - (XT_SZ + H2_SZ);
  if (f >= 0 && f < NBLK + 1) flags[f] = 0u;   // flags[257] (isf) preserved
}

// ---------------------------------------------------------------------------
// grid barrier — cache-maintenance ONCE PER BLOCK (tid 0), not per wave.
// (round-3 verified: 75ms -> 31.8ms vs per-wave fences. Do not touch.)
// ---------------------------------------------------------------------------
__device__ __forceinline__ void grid_barrier(unsigned* flags, unsigned* gen, unsigned target) {
  __syncthreads();   // all waves' global stores drained to L2
  const int tid = threadIdx.x;
  if (blockIdx.x == 0) {
    if (tid > 0) {
      long spin = 0;
      while (__hip_atomic_load(&flags[tid], __ATOMIC_RELAXED, __HIP_MEMORY_SCOPE_AGENT) < target) {
        __builtin_amdgcn_s_sleep(2);
        if (++spin > (1L << 24)) break;  // bail-out: never expected (co-resident)
      }
    }
    __syncthreads();
    if (tid == 0) {
      __threadfence();  // release (flush block0 data) + acquire (see others' data)
      __hip_atomic_store(gen, target, __ATOMIC_RELEASE, __HIP_MEMORY_SCOPE_AGENT);
    }
    __syncthreads();
  } else {
    if (tid == 0) {
      __threadfence();  // release: publish this block's phase output
      __hip_atomic_store(&flags[blockIdx.x], target, __ATOMIC_RELEASE, __HIP_MEMORY_SCOPE_AGENT);
      long spin = 0;
      while (__hip_atomic_load(gen, __ATOMIC_RELAXED, __HIP_MEMORY_SCOPE_AGENT) < target) {
        __builtin_amdgcn_s_sleep(2);
        if (++spin > (1L << 24)) break;
      }
      __threadfence();  // acquire: invalidate stale L1/L2 before block reads
    }
    __syncthreads();
  }
}

// ---- deep-MLP register-tile macros -----------------------------------------
// LD64: issue 64 independent column loads (stride BB floats) into a statically
// indexed register array -> 64 outstanding L2/L3 misses instead of ~8.
#define LD64(BUF, PTR, ROW0) \
  { _Pragma("unroll") for (int j = 0; j < 64; ++j) BUF[j] = (PTR)[((ROW0) + j) * BB]; }
// CP1: consume one 64-row chunk against 4 weight rows (GEMM1)
#define CP1(BUF, K) \
  { _Pragma("unroll") for (int j = 0; j < 16; ++j) { \
      const int qI = (K) * 16 + j; \
      float4 u0 = q0[qI], u1 = q1[qI], u2 = q2[qI], u3 = q3[qI]; \
      float x0 = BUF[4*j], x1 = BUF[4*j+1], x2 = BUF[4*j+2], x3 = BUF[4*j+3]; \
      a0 += u0.x*x0 + u0.y*x1 + u0.z*x2 + u0.w*x3; \
      a1 += u1.x*x0 + u1.y*x1 + u1.z*x2 + u1.w*x3; \
      a2 += u2.x*x0 + u2.y*x1 + u2.z*x2 + u2.w*x3; \
      a3 += u3.x*x0 + u3.y*x1 + u3.z*x2 + u3.w*x3; } }
// CP2: consume one 64-row chunk against 2 weight rows (out-GEMM / GEMM2)
#define CP2(BUF, K) \
  { _Pragma("unroll") for (int j = 0; j < 16; ++j) { \
      const int qI = (K) * 16 + j; \
      float4 u0 = r0[qI], u1 = r1[qI]; \
      float x0 = BUF[4*j], x1 = BUF[4*j+1], x2 = BUF[4*j+2], x3 = BUF[4*j+3]; \
      a0 += u0.x*x0 + u0.y*x1 + u0.z*x2 + u0.w*x3; \
      a1 += u1.x*x0 + u1.y*x1 + u1.z*x2 + u1.w*x3; } }

// ---------------------------------------------------------------------------
// persistent decoder
// ---------------------------------------------------------------------------
__global__ void __launch_bounds__(NTHR, 1) decoder_kernel(
    const void* __restrict__ enc_key,
    const void* __restrict__ enc_value,
    const int*  __restrict__ enc_len,
    const int*  __restrict__ y,
    const void* __restrict__ emb,
    const void* __restrict__ w_ih1, const void* __restrict__ w_hh1,
    const void* __restrict__ b_ih1, const void* __restrict__ b_hh1,
    const void* __restrict__ w_ih2, const void* __restrict__ w_hh2,
    const void* __restrict__ b_ih2, const void* __restrict__ b_hh2,
    const void* __restrict__ w_out, const void* __restrict__ b_out,
    void* __restrict__ out, float* __restrict__ ws)
{
  // persistent weight slices (fp32, loaded once; reads are wave-uniform broadcasts)
  __shared__ float sW1[8][D1];      // block w owns hu=2w,2w+1: rows 4h+g  (28.7 KB)
  __shared__ float sW2[4][640];     // blocks<128 own layer2 hidden w      (10.2 KB)
  __shared__ float sWo[4][256];     // block w owns vocab rows 4w..4w+3    (4 KB)
  __shared__ float sB1[8];
  __shared__ float sB2[4];
  __shared__ float sBo[4];
  __shared__ float sRed[4];
  __shared__ float sAttn[TT];
  __shared__ float sH2[KVD];
  __shared__ float sGex[2][BB];

  const int tid = threadIdx.x;
  const int w   = blockIdx.x;
  unsigned* flags = (unsigned*)(ws + FLAG_OFF);
  unsigned* gen   = flags + NBLK;
  const bool isf  = flags[NBLK + 1] != 0;   // written by probe_kernel

  // ---- one-time LDS weight staging (-> fp32) ----
  for (int i = tid; i < 8 * D1; i += NTHR) {
    int r = i / D1, k = i - r * D1;        // r = 4h+g
    int g = r & 3, h = r >> 2;
    int R = g * HH + 2 * w + h;            // global gate row in [0,2048)
    sW1[r][k] = (k < EE + KVD) ? ldx(w_ih1, (size_t)R * (EE + KVD) + k, isf)
                               : ldx(w_hh1, (size_t)R * HH + (k - (EE + KVD)), isf);
  }
  if (tid < 8) {
    int R = (tid & 3) * HH + 2 * w + (tid >> 2);
    sB1[tid] = ldx(b_ih1, R, isf) + ldx(b_hh1, R, isf);
  }
  if (w < BB) {
    for (int i = tid; i < 4 * 640; i += NTHR) {
      int g = i / 640, k = i - g * 640;
      int R = g * KVD + w;                 // global gate row in [0,512)
      sW2[g][k] = (k < HH) ? ldx(w_ih2, (size_t)R * HH + k, isf)
                           : ldx(w_hh2, (size_t)R * KVD + (k - HH), isf);
    }
    if (tid < 4) {
      int R = tid * KVD + w;
      sB2[tid] = ldx(b_ih2, R, isf) + ldx(b_hh2, R, isf);
    }
  }
  for (int i = tid; i < 4 * 256; i += NTHR) {
    int r = i >> 8, d = i & 255;
    sWo[r][d] = ldx(w_out, (size_t)(4 * w + r) * 256 + d, isf);
  }
  if (tid < 4) sBo[tid] = ldx(b_out, 4 * w + tid, isf);
  __syncthreads();

  const int b  = tid & 127;   // batch column
  const int hi = tid >> 7;    // half: 0/1
  float c1 = 0.0f;            // c1[hu=2w+hi][b] lives here across all steps
  float c2 = 0.0f;            // (w<128, hi==0): c2[w][b]

  unsigned target = 0;

  for (int t = 0; t <= LL; ++t) {
    const int p0 = t & 1;
    float* xT0  = ws + XT_OFF + p0 * XT_SZ;
    float* xT1  = ws + XT_OFF + (p0 ^ 1) * XT_SZ;
    float* h2T0 = ws + H2_OFF + p0 * H2_SZ;
    float* h2T1 = ws + H2_OFF + (p0 ^ 1) * H2_SZ;

    // ================= Phase A =================
    if (t > 0) {
      // output GEMM for step t-1: logits = [h2, context] @ w_out^T + b_out
      // 4 chunks of 64 rows, double-buffered register tiles (deep MLP).
      float a0 = sBo[2 * hi], a1 = sBo[2 * hi + 1];
      const float4* r0 = (const float4*)&sWo[2 * hi][0];
      const float4* r1 = (const float4*)&sWo[2 * hi + 1][0];
      const float* hp = h2T0 + b;
      const float* cp = xT0 + 256 * BB + b;
      float xa[64], xb[64];
      LD64(xa, hp, 0)
      LD64(xb, hp, 64)  CP2(xa, 0)
      LD64(xa, cp, 0)   CP2(xb, 1)
      LD64(xb, cp, 64)  CP2(xa, 2)
                        CP2(xb, 3)
      int v = 4 * w + 2 * hi;
      size_t oidx = (size_t)b * (LL * VV) + (size_t)(t - 1) * VV + v;
      stx(out, oidx, a0, isf);
      stx(out, oidx + 1, a1, isf);
    }
    if (t == LL) break;                                   // final epilogue done

    {
      // GEMM1 + LSTM1 for step t: x = [emb_t, context, h1] (rows of xT0)
      // 14 chunks of 64 rows, double-buffered: 64 loads in flight covers
      // post-inv L3 latency (~800cy) under 128 FMAs/chunk of compute.
      const int hu = 2 * w + hi;
      float a0 = sB1[4 * hi + 0], a1 = sB1[4 * hi + 1];
      float a2 = sB1[4 * hi + 2], a3 = sB1[4 * hi + 3];
      const float4* q0 = (const float4*)&sW1[4 * hi + 0][0];
      const float4* q1 = (const float4*)&sW1[4 * hi + 1][0];
      const float4* q2 = (const float4*)&sW1[4 * hi + 2][0];
      const float4* q3 = (const float4*)&sW1[4 * hi + 3][0];
      const float* xp = xT0 + b;
      float xa[64], xb[64];
      LD64(xa, xp, 0)
      LD64(xb, xp, 64)   CP1(xa, 0)
      LD64(xa, xp, 128)  CP1(xb, 1)
      LD64(xb, xp, 192)  CP1(xa, 2)
      LD64(xa, xp, 256)  CP1(xb, 3)
      LD64(xb, xp, 320)  CP1(xa, 4)
      LD64(xa, xp, 384)  CP1(xb, 5)
      LD64(xb, xp, 448)  CP1(xa, 6)
      LD64(xa, xp, 512)  CP1(xb, 7)
      LD64(xb, xp, 576)  CP1(xa, 8)
      LD64(xa, xp, 640)  CP1(xb, 9)
      LD64(xb, xp, 704)  CP1(xa, 10)
      LD64(xa, xp, 768)  CP1(xb, 11)
      LD64(xb, xp, 832)  CP1(xa, 12)
                         CP1(xb, 13)
      float ig = sigm(a0), fg = sigm(a1), gg = tanhf(a2), og = sigm(a3);
      c1 = fg * c1 + ig * gg;
      float h1v = og * tanhf(c1);
      xT1[(384 + hu) * BB + b] = h1v;
    }
    grid_barrier(flags, gen, ++target);

    // ================= Phase B =================
    if (w < BB) {
      // GEMM2 + LSTM2: gates2 = [h1(512), h2(128)] @ W2^T ; 10 chunks of 64
      float a0 = sB2[2 * hi], a1 = sB2[2 * hi + 1];
      const float4* r0 = (const float4*)&sW2[2 * hi][0];
      const float4* r1 = (const float4*)&sW2[2 * hi + 1][0];
      const float* xp = xT1 + 384 * BB + b;   // h1(t)
      const float* hp = h2T0 + b;             // h2(t-1)
      float xa[64], xb[64];
      LD64(xa, xp, 0)
      LD64(xb, xp, 64)   CP2(xa, 0)
      LD64(xa, xp, 128)  CP2(xb, 1)
      LD64(xb, xp, 192)  CP2(xa, 2)
      LD64(xa, xp, 256)  CP2(xb, 3)
      LD64(xb, xp, 320)  CP2(xa, 4)
      LD64(xa, xp, 384)  CP2(xb, 5)
      LD64(xb, xp, 448)  CP2(xa, 6)
      LD64(xa, hp, 0)    CP2(xb, 7)
      LD64(xb, hp, 64)   CP2(xa, 8)
                         CP2(xb, 9)
      if (hi == 1) { sGex[0][b] = tanhf(a0); sGex[1][b] = sigm(a1); }  // g, o
      __syncthreads();
      if (hi == 0) {                                                   // i, f
        c2 = sigm(a1) * c2 + sigm(a0) * sGex[0][b];
        float h2v = sGex[1][b] * tanhf(c2);
        h2T1[w * BB + b] = h2v;
      }
    } else {
      // embedding gather for step t+1 (teacher forcing: token y[:, t])
      int j = w - BB;
      int tok = y[j * LL + t];
      xT1[tid * BB + j] = ldx(emb, (size_t)tok * EE + tid, isf);  // tid in [0,256)=E
    }
    grid_barrier(flags, gen, ++target);

    // ================= Phase C =================
    if (w < BB) {
      const int rb = w;                                  // batch row pinned to block
      if (tid < KVD) sH2[tid] = h2T1[tid * BB + rb];
      __syncthreads();
      const int len = enc_len[rb];
      float lmax = -3.0e38f;
      #pragma unroll
      for (int rep = 0; rep < 2; ++rep) {
        int tp = tid + rep * 256;
        float e = -3.0e38f;
        if (tp < TT) {
          float acc = 0.0f;
          if (isf) {
            const float4* kr = (const float4*)((const float*)enc_key + ((size_t)rb * TT + tp) * KVD);
            #pragma unroll 8
            for (int q = 0; q < 32; ++q) {
              float4 u = kr[q];
              acc += u.x * sH2[4 * q + 0] + u.y * sH2[4 * q + 1]
                   + u.z * sH2[4 * q + 2] + u.w * sH2[4 * q + 3];
            }
          } else {
            // 16B loads: 16 independent uint4 (=8 bf16 each)
            const uint4* kr = (const uint4*)((const ushort_t*)enc_key + ((size_t)rb * TT + tp) * KVD);
            #pragma unroll
            for (int q = 0; q < 16; ++q) {
              uint4 u = kr[q];
              acc += lo16(u.x) * sH2[8 * q + 0] + hi16(u.x) * sH2[8 * q + 1]
                   + lo16(u.y) * sH2[8 * q + 2] + hi16(u.y) * sH2[8 * q + 3]
                   + lo16(u.z) * sH2[8 * q + 4] + hi16(u.z) * sH2[8 * q + 5]
                   + lo16(u.w) * sH2[8 * q + 6] + hi16(u.w) * sH2[8 * q + 7];
            }
          }
          e = (tp < len) ? acc : -1e9f;
          sAttn[tp] = e;
        }
        lmax = fmaxf(lmax, e);
      }
      for (int off = 32; off > 0; off >>= 1) lmax = fmaxf(lmax, __shfl_down(lmax, off, 64));
      if ((tid & 63) == 0) sRed[tid >> 6] = lmax;
      __syncthreads();
      const float m = fmaxf(fmaxf(sRed[0], sRed[1]), fmaxf(sRed[2], sRed[3]));
      float lsum = 0.0f;
      #pragma unroll
      for (int rep = 0; rep < 2; ++rep) {
        int tp = tid + rep * 256;
        if (tp < TT) { float a = expf(sAttn[tp] - m); sAttn[tp] = a; lsum += a; }
      }
      for (int off = 32; off > 0; off >>= 1) lsum += __shfl_down(lsum, off, 64);
      __syncthreads();
      if ((tid & 63) == 0) sRed[tid >> 6] = lsum;
      __syncthreads();
      const float rS = 1.0f / (sRed[0] + sRed[1] + sRed[2] + sRed[3]);
      #pragma unroll
      for (int rep = 0; rep < 2; ++rep) {
        int tp = tid + rep * 256;
        if (tp < TT) {
          float a = sAttn[tp] * rS;
          sAttn[tp] = a;
          if (rb == 0) stx(out, (size_t)PLOT_OFF + (size_t)t * TT + tp, a, isf);  // attn_plot
        }
      }
      __syncthreads();
      {
        // context = attn @ enc_value ; 4 chunks of 50 rows, double-buffered
        const int d = tid & 127, half = tid >> 7;
        const int tb = half * 200;
        float accv[4] = {0.0f, 0.0f, 0.0f, 0.0f};
        float va[50], vb[50];
        if (isf) {
          const float* vc = (const float*)enc_value + ((size_t)rb * TT + tb) * KVD + d;
          #pragma unroll
          for (int j = 0; j < 50; ++j) va[j] = vc[(size_t)j * KVD];
          #pragma unroll
          for (int j = 0; j < 50; ++j) vb[j] = vc[(size_t)(50 + j) * KVD];
          #pragma unroll
          for (int j = 0; j < 50; ++j) accv[j & 3] += sAttn[tb + j] * va[j];
          #pragma unroll
          for (int j = 0; j < 50; ++j) va[j] = vc[(size_t)(100 + j) * KVD];
          #pragma unroll
          for (int j = 0; j < 50; ++j) accv[j & 3] += sAttn[tb + 50 + j] * vb[j];
          #pragma unroll
          for (int j = 0; j < 50; ++j) vb[j] = vc[(size_t)(150 + j) * KVD];
          #pragma unroll
          for (int j = 0; j < 50; ++j) accv[j & 3] += sAttn[tb + 100 + j] * va[j];
          #pragma unroll
          for (int j = 0; j < 50; ++j) accv[j & 3] += sAttn[tb + 150 + j] * vb[j];
        } else {
          const ushort_t* vc = (const ushort_t*)enc_value + ((size_t)rb * TT + tb) * KVD + d;
          #pragma unroll
          for (int j = 0; j < 50; ++j) va[j] = bf2f(vc[(size_t)j * KVD]);
          #pragma unroll
          for (int j = 0; j < 50; ++j) vb[j] = bf2f(vc[(size_t)(50 + j) * KVD]);
          #pragma unroll
          for (int j = 0; j < 50; ++j) accv[j & 3] += sAttn[tb + j] * va[j];
          #pragma unroll
          for (int j = 0; j < 50; ++j) va[j] = bf2f(vc[(size_t)(100 + j) * KVD]);
          #pragma unroll
          for (int j = 0; j < 50; ++j) accv[j & 3] += sAttn[tb + 50 + j] * vb[j];
          #pragma unroll
          for (int j = 0; j < 50; ++j) vb[j] = bf2f(vc[(size_t)(150 + j) * KVD]);
          #pragma unroll
          for (int j = 0; j < 50; ++j) accv[j & 3] += sAttn[tb + 100 + j] * va[j];
          #pragma unroll
          for (int j = 0; j < 50; ++j) accv[j & 3] += sAttn[tb + 150 + j] * vb[j];
        }
        float acc = (accv[0] + accv[1]) + (accv[2] + accv[3]);
        if (half == 1) sGex[0][d] = acc;
        __syncthreads();
        if (half == 0) xT1[(256 + d) * BB + rb] = acc + sGex[0][d];
      }
    }
    grid_barrier(flags, gen, ++target);
  }
}

extern "C" void kernel_launch(void* const* d_in, const int* in_sizes, int n_in,
                              void* d_out, int out_size, void* d_ws, size_t ws_size,
                              hipStream_t stream) {
  const void* enc_key   = d_in[0];
  const void* enc_value = d_in[1];
  const int*  enc_len   = (const int*)d_in[2];
  const int*  y         = (const int*)d_in[3];
  const void* emb       = d_in[4];
  const void* w_ih1     = d_in[5];
  const void* w_hh1     = d_in[6];
  const void* b_ih1     = d_in[7];
  const void* b_hh1     = d_in[8];
  const void* w_ih2     = d_in[9];
  const void* w_hh2     = d_in[10];
  const void* b_ih2     = d_in[11];
  const void* b_hh2     = d_in[12];
  const void* w_out     = d_in[13];
  const void* b_out     = d_in[14];
  float* ws = (float*)d_ws;

  // 1) detect fp32 vs bf16 (writes isf flag into ws)
  probe_kernel<<<dim3(1), dim3(64), 0, stream>>>(w_out, ws);
  // 2) zero state/barrier region, seed <sos> embedding (reads isf)
  init_kernel<<<dim3((XT_SZ + H2_SZ + NBLK + 1 + NTHR - 1) / NTHR), dim3(NTHR), 0, stream>>>(emb, ws);
  // 3) persistent decode
  decoder_kernel<<<dim3(NBLK), dim3(NTHR), 0, stream>>>(
      enc_key, enc_value, enc_len, y, emb,
      w_ih1, w_hh1, b_ih1, b_hh1,
      w_ih2, w_hh2, b_ih2, b_hh2,
      w_out, b_out, d_out, ws);
}

// Round 5
// 50329.123 us; speedup vs baseline: 5.0889x; 5.0889x over previous
//
#include <hip/hip_runtime.h>
#include <hip/hip_bf16.h>

// Problem constants
#define BB   128   // batch
#define TT   400   // encoder length
#define KVD  128   // key/value dim (= layer2 hidden)
#define VV   1024  // vocab
#define EE   256   // embed dim
#define HH   512   // layer1 hidden
#define LL   300   // decode length
#define D1   896   // E + KV + H (layer1 input incl. recurrent)
#define NBLK 256
#define NTHR 256

// workspace layout (float units)
#define XT_SZ   (D1 * BB)             // 114688 floats per parity buffer
#define XT_OFF  0                     // 2 buffers
#define H2_SZ   (KVD * BB)            // 16384 floats per parity buffer
#define H2_OFF  (2 * XT_SZ)           // 229376
#define FLAG_OFF (H2_OFF + 2 * H2_SZ) // unsigned flags[256] + gen + isf
#define PLOT_OFF (BB * LL * VV)       // 39321600 (attn_plot offset in out)

typedef unsigned short ushort_t;

__device__ __forceinline__ float bf2f(ushort_t u) {
  return __uint_as_float(((unsigned)u) << 16);
}
__device__ __forceinline__ ushort_t f2bf(float f) {
  unsigned u = __float_as_uint(f);
  return (ushort_t)((u + 0x7FFFu + ((u >> 16) & 1u)) >> 16);  // RNE
}
__device__ __forceinline__ float sigm(float x) { return 1.0f / (1.0f + expf(-x)); }

// dtype-agnostic element load/store (isf: buffer is fp32, else bf16)
__device__ __forceinline__ float ldx(const void* p, size_t i, bool isf) {
  return isf ? ((const float*)p)[i] : bf2f(((const ushort_t*)p)[i]);
}
__device__ __forceinline__ void stx(void* p, size_t i, float v, bool isf) {
  if (isf) ((float*)p)[i] = v; else ((ushort_t*)p)[i] = f2bf(v);
}

// ---------------------------------------------------------------------------
// probe: decide whether float tensors are fp32 or bf16.
// ---------------------------------------------------------------------------
__global__ void probe_kernel(const void* __restrict__ w_out, float* __restrict__ ws) {
  if (blockIdx.x == 0 && threadIdx.x == 0) {
    const ushort_t* p = (const ushort_t*)w_out;
    int bad = 0;
    for (int i = 0; i < 512; ++i) {
      float v = bf2f(p[i]);
      if (!(fabsf(v) < 0.5f)) bad++;   // counts NaN/inf too
    }
    unsigned* flags = (unsigned*)(ws + FLAG_OFF);
    flags[NBLK + 1] = (bad > 0) ? 1u : 0u;
  }
}

// ---------------------------------------------------------------------------
// init: zero parity-0 state, seed <sos> embedding, zero barrier flags
// ---------------------------------------------------------------------------
__global__ void __launch_bounds__(NTHR) init_kernel(const void* __restrict__ emb,
                                                    float* __restrict__ ws) {
  unsigned* flags = (unsigned*)(ws + FLAG_OFF);
  const bool isf = flags[NBLK + 1] != 0;
  int idx = blockIdx.x * NTHR + threadIdx.x;
  if (idx < XT_SZ) {
    int k = idx >> 7;  // row of xT (col = idx & 127)
    ws[XT_OFF + idx] = (k < EE) ? ldx(emb, EE + k, isf) : 0.0f;  // SOS token = 1
  }
  int j = idx - XT_SZ;
  if (j >= 0 && j < H2_SZ) ws[H2_OFF + j] = 0.0f;
  int f = idx - (XT_SZ + H2_SZ);
  if (f >= 0 && f < NBLK + 1) flags[f] = 0u;   // flags[257] (isf) preserved
}

// ---------------------------------------------------------------------------
// grid barrier — cache-maintenance ONCE PER BLOCK (tid 0), not per wave.
// (round-3 verified: 75ms -> 31.8ms vs per-wave fences. Do not touch.)
// ---------------------------------------------------------------------------
__device__ __forceinline__ void grid_barrier(unsigned* flags, unsigned* gen, unsigned target) {
  __syncthreads();   // all waves' global stores drained to L2
  const int tid = threadIdx.x;
  if (blockIdx.x == 0) {
    if (tid > 0) {
      long spin = 0;
      while (__hip_atomic_load(&flags[tid], __ATOMIC_RELAXED, __HIP_MEMORY_SCOPE_AGENT) < target) {
        __builtin_amdgcn_s_sleep(2);
        if (++spin > (1L << 24)) break;  // bail-out: never expected (co-resident)
      }
    }
    __syncthreads();
    if (tid == 0) {
      __threadfence();  // release (flush block0 data) + acquire (see others' data)
      __hip_atomic_store(gen, target, __ATOMIC_RELEASE, __HIP_MEMORY_SCOPE_AGENT);
    }
    __syncthreads();
  } else {
    if (tid == 0) {
      __threadfence();  // release: publish this block's phase output
      __hip_atomic_store(&flags[blockIdx.x], target, __ATOMIC_RELEASE, __HIP_MEMORY_SCOPE_AGENT);
      long spin = 0;
      while (__hip_atomic_load(gen, __ATOMIC_RELAXED, __HIP_MEMORY_SCOPE_AGENT) < target) {
        __builtin_amdgcn_s_sleep(2);
        if (++spin > (1L << 24)) break;
      }
      __threadfence();  // acquire: invalidate stale L1/L2 before block reads
    }
    __syncthreads();
  }
}

// ---- cooperative LDS chunk staging -----------------------------------------
// A chunk = 32 activation rows x 128 batch cols = 16 KB, CONTIGUOUS in the
// row-major xT/h2T layout. 256 threads fetch it as 4 coalesced float4 each
// (16 VGPR double-buffer), write to sX, and the GEMV inner loop reads LDS
// (2-way bank aliasing = free). Replaces per-thread 512B-stride column walks
// (1 dword/row, latency-serialized) with wave-coalesced 16B loads whose
// latency hides under the previous chunk's compute.
#define STAGE_LOAD(PF, SRC4, C) \
  { _Pragma("unroll") for (int j = 0; j < 4; ++j) PF[j] = (SRC4)[(size_t)(C) * 1024 + j * 256 + tid]; }
#define STAGE_WRITE(PF) \
  { float4* s4 = (float4*)sX; _Pragma("unroll") for (int j = 0; j < 4; ++j) s4[j * 256 + tid] = PF[j]; }
// consume chunk against 4 weight rows (GEMM1); WB = float4 weight base index
#define CHUNK_CP4(WB) \
  { _Pragma("unroll") for (int q = 0; q < 8; ++q) { \
      float x0 = sX[(4*q+0)*128 + b], x1 = sX[(4*q+1)*128 + b]; \
      float x2 = sX[(4*q+2)*128 + b], x3 = sX[(4*q+3)*128 + b]; \
      float4 u0 = q0[(WB)+q], u1 = q1[(WB)+q], u2 = q2[(WB)+q], u3 = q3[(WB)+q]; \
      a0 += u0.x*x0 + u0.y*x1 + u0.z*x2 + u0.w*x3; \
      a1 += u1.x*x0 + u1.y*x1 + u1.z*x2 + u1.w*x3; \
      a2 += u2.x*x0 + u2.y*x1 + u2.z*x2 + u2.w*x3; \
      a3 += u3.x*x0 + u3.y*x1 + u3.z*x2 + u3.w*x3; } }
// consume chunk against 2 weight rows (out-GEMM / GEMM2)
#define CHUNK_CP2(WB) \
  { _Pragma("unroll") for (int q = 0; q < 8; ++q) { \
      float x0 = sX[(4*q+0)*128 + b], x1 = sX[(4*q+1)*128 + b]; \
      float x2 = sX[(4*q+2)*128 + b], x3 = sX[(4*q+3)*128 + b]; \
      float4 u0 = r0[(WB)+q], u1 = r1[(WB)+q]; \
      a0 += u0.x*x0 + u0.y*x1 + u0.z*x2 + u0.w*x3; \
      a1 += u1.x*x0 + u1.y*x1 + u1.z*x2 + u1.w*x3; } }

// ---------------------------------------------------------------------------
// persistent decoder
// ---------------------------------------------------------------------------
__global__ void __launch_bounds__(NTHR) decoder_kernel(
    const void* __restrict__ enc_key,
    const void* __restrict__ enc_value,
    const int*  __restrict__ enc_len,
    const int*  __restrict__ y,
    const void* __restrict__ emb,
    const void* __restrict__ w_ih1, const void* __restrict__ w_hh1,
    const void* __restrict__ b_ih1, const void* __restrict__ b_hh1,
    const void* __restrict__ w_ih2, const void* __restrict__ w_hh2,
    const void* __restrict__ b_ih2, const void* __restrict__ b_hh2,
    const void* __restrict__ w_out, const void* __restrict__ b_out,
    void* __restrict__ out, float* __restrict__ ws)
{
  // persistent weight slices (fp32, loaded once; reads are wave-uniform broadcasts)
  __shared__ float sW1[8][D1];      // block w owns hu=2w,2w+1: rows 4h+g  (28.7 KB)
  __shared__ float sW2[4][640];     // blocks<128 own layer2 hidden w      (10.2 KB)
  __shared__ float sWo[4][256];     // block w owns vocab rows 4w..4w+3    (4 KB)
  __shared__ float sB1[8];
  __shared__ float sB2[4];
  __shared__ float sBo[4];
  __shared__ float sRed[4];
  __shared__ float sAttn[TT];
  __shared__ float sH2[KVD];
  __shared__ float sGex[2][BB];
  __shared__ float sX[32 * 128];    // chunk staging buffer (16 KB) -> total 62.6 KB

  const int tid = threadIdx.x;
  const int w   = blockIdx.x;
  unsigned* flags = (unsigned*)(ws + FLAG_OFF);
  unsigned* gen   = flags + NBLK;
  const bool isf  = flags[NBLK + 1] != 0;   // written by probe_kernel

  // ---- one-time LDS weight staging (-> fp32) ----
  for (int i = tid; i < 8 * D1; i += NTHR) {
    int r = i / D1, k = i - r * D1;        // r = 4h+g
    int g = r & 3, h = r >> 2;
    int R = g * HH + 2 * w + h;            // global gate row in [0,2048)
    sW1[r][k] = (k < EE + KVD) ? ldx(w_ih1, (size_t)R * (EE + KVD) + k, isf)
                               : ldx(w_hh1, (size_t)R * HH + (k - (EE + KVD)), isf);
  }
  if (tid < 8) {
    int R = (tid & 3) * HH + 2 * w + (tid >> 2);
    sB1[tid] = ldx(b_ih1, R, isf) + ldx(b_hh1, R, isf);
  }
  if (w < BB) {
    for (int i = tid; i < 4 * 640; i += NTHR) {
      int g = i / 640, k = i - g * 640;
      int R = g * KVD + w;                 // global gate row in [0,512)
      sW2[g][k] = (k < HH) ? ldx(w_ih2, (size_t)R * HH + k, isf)
                           : ldx(w_hh2, (size_t)R * KVD + (k - HH), isf);
    }
    if (tid < 4) {
      int R = tid * KVD + w;
      sB2[tid] = ldx(b_ih2, R, isf) + ldx(b_hh2, R, isf);
    }
  }
  for (int i = tid; i < 4 * 256; i += NTHR) {
    int r = i >> 8, d = i & 255;
    sWo[r][d] = ldx(w_out, (size_t)(4 * w + r) * 256 + d, isf);
  }
  if (tid < 4) sBo[tid] = ldx(b_out, 4 * w + tid, isf);
  __syncthreads();

  const int b  = tid & 127;   // batch column
  const int hi = tid >> 7;    // half: 0/1
  float c1 = 0.0f;            // c1[hu=2w+hi][b] lives here across all steps
  float c2 = 0.0f;            // (w<128, hi==0): c2[w][b]

  unsigned target = 0;

  for (int t = 0; t <= LL; ++t) {
    const int p0 = t & 1;
    float* xT0  = ws + XT_OFF + p0 * XT_SZ;
    float* xT1  = ws + XT_OFF + (p0 ^ 1) * XT_SZ;
    float* h2T0 = ws + H2_OFF + p0 * H2_SZ;
    float* h2T1 = ws + H2_OFF + (p0 ^ 1) * H2_SZ;

    // ================= Phase A =================
    if (t > 0) {
      // output GEMM for step t-1: logits = [h2(128) | context(128)] @ w_out^T
      // 8 chunks of 32 rows, LDS-staged. Row order identical to round-3.
      float a0 = sBo[2 * hi], a1 = sBo[2 * hi + 1];
      const float4* r0 = (const float4*)&sWo[2 * hi][0];
      const float4* r1 = (const float4*)&sWo[2 * hi + 1][0];
      const float4* hsrc = (const float4*)h2T0;
      const float4* csrc = (const float4*)(xT0 + 256 * BB);
      float4 pf[4];
      STAGE_LOAD(pf, hsrc, 0)
      for (int c = 0; c < 8; ++c) {
        __syncthreads();            // previous chunk's compute done
        STAGE_WRITE(pf)
        if (c < 7) {                // prefetch next chunk under this compute
          if (c < 3) STAGE_LOAD(pf, hsrc, c + 1)
          else       STAGE_LOAD(pf, csrc, c - 3)
        }
        __syncthreads();            // sX visible
        CHUNK_CP2(c * 8)
      }
      int v = 4 * w + 2 * hi;
      size_t oidx = (size_t)b * (LL * VV) + (size_t)(t - 1) * VV + v;
      stx(out, oidx, a0, isf);
      stx(out, oidx + 1, a1, isf);
    }
    if (t == LL) break;                                   // final epilogue done

    {
      // GEMM1 + LSTM1 for step t: x = [emb_t, context, h1] (rows of xT0)
      // 28 chunks of 32 rows, LDS-staged.
      const int hu = 2 * w + hi;
      float a0 = sB1[4 * hi + 0], a1 = sB1[4 * hi + 1];
      float a2 = sB1[4 * hi + 2], a3 = sB1[4 * hi + 3];
      const float4* q0 = (const float4*)&sW1[4 * hi + 0][0];
      const float4* q1 = (const float4*)&sW1[4 * hi + 1][0];
      const float4* q2 = (const float4*)&sW1[4 * hi + 2][0];
      const float4* q3 = (const float4*)&sW1[4 * hi + 3][0];
      const float4* xsrc = (const float4*)xT0;
      float4 pf[4];
      STAGE_LOAD(pf, xsrc, 0)
      for (int c = 0; c < 28; ++c) {
        __syncthreads();
        STAGE_WRITE(pf)
        if (c < 27) STAGE_LOAD(pf, xsrc, c + 1)
        __syncthreads();
        CHUNK_CP4(c * 8)
      }
      float ig = sigm(a0), fg = sigm(a1), gg = tanhf(a2), og = sigm(a3);
      c1 = fg * c1 + ig * gg;
      float h1v = og * tanhf(c1);
      xT1[(384 + hu) * BB + b] = h1v;
    }
    grid_barrier(flags, gen, ++target);

    // ================= Phase B =================
    if (w < BB) {
      // GEMM2 + LSTM2: gates2 = [h1(512) | h2(128)] @ W2^T ; 20 chunks of 32
      float a0 = sB2[2 * hi], a1 = sB2[2 * hi + 1];
      const float4* r0 = (const float4*)&sW2[2 * hi][0];
      const float4* r1 = (const float4*)&sW2[2 * hi + 1][0];
      const float4* xsrc = (const float4*)(xT1 + 384 * BB);  // h1(t)
      const float4* hsrc = (const float4*)h2T0;              // h2(t-1)
      float4 pf[4];
      STAGE_LOAD(pf, xsrc, 0)
      for (int c = 0; c < 20; ++c) {
        __syncthreads();
        STAGE_WRITE(pf)
        if (c < 19) {
          if (c < 15) STAGE_LOAD(pf, xsrc, c + 1)
          else        STAGE_LOAD(pf, hsrc, c - 15)
        }
        __syncthreads();
        CHUNK_CP2(c * 8)
      }
      if (hi == 1) { sGex[0][b] = tanhf(a0); sGex[1][b] = sigm(a1); }  // g, o
      __syncthreads();
      if (hi == 0) {                                                   // i, f
        c2 = sigm(a1) * c2 + sigm(a0) * sGex[0][b];
        float h2v = sGex[1][b] * tanhf(c2);
        h2T1[w * BB + b] = h2v;
      }
    } else {
      // embedding gather for step t+1 (teacher forcing: token y[:, t])
      int j = w - BB;
      int tok = y[j * LL + t];
      xT1[tid * BB + j] = ldx(emb, (size_t)tok * EE + tid, isf);  // tid in [0,256)=E
    }
    grid_barrier(flags, gen, ++target);

    // ================= Phase C =================
    if (w < BB) {
      const int rb = w;                                  // batch row pinned to block
      if (tid < KVD) sH2[tid] = h2T1[tid * BB + rb];
      __syncthreads();
      const int len = enc_len[rb];
      float lmax = -3.0e38f;
      #pragma unroll
      for (int rep = 0; rep < 2; ++rep) {
        int tp = tid + rep * 256;
        float e = -3.0e38f;
        if (tp < TT) {
          float acc = 0.0f;
          if (isf) {
            const float4* kr = (const float4*)((const float*)enc_key + ((size_t)rb * TT + tp) * KVD);
            #pragma unroll 8
            for (int q = 0; q < 32; ++q) {
              float4 u = kr[q];
              acc += u.x * sH2[4 * q + 0] + u.y * sH2[4 * q + 1]
                   + u.z * sH2[4 * q + 2] + u.w * sH2[4 * q + 3];
            }
          } else {
            const ushort4* kr = (const ushort4*)((const ushort_t*)enc_key + ((size_t)rb * TT + tp) * KVD);
            #pragma unroll 8
            for (int q = 0; q < 32; ++q) {
              ushort4 u = kr[q];
              acc += bf2f(u.x) * sH2[4 * q + 0] + bf2f(u.y) * sH2[4 * q + 1]
                   + bf2f(u.z) * sH2[4 * q + 2] + bf2f(u.w) * sH2[4 * q + 3];
            }
          }
          e = (tp < len) ? acc : -1e9f;
          sAttn[tp] = e;
        }
        lmax = fmaxf(lmax, e);
      }
      for (int off = 32; off > 0; off >>= 1) lmax = fmaxf(lmax, __shfl_down(lmax, off, 64));
      if ((tid & 63) == 0) sRed[tid >> 6] = lmax;
      __syncthreads();
      const float m = fmaxf(fmaxf(sRed[0], sRed[1]), fmaxf(sRed[2], sRed[3]));
      float lsum = 0.0f;
      #pragma unroll
      for (int rep = 0; rep < 2; ++rep) {
        int tp = tid + rep * 256;
        if (tp < TT) { float a = expf(sAttn[tp] - m); sAttn[tp] = a; lsum += a; }
      }
      for (int off = 32; off > 0; off >>= 1) lsum += __shfl_down(lsum, off, 64);
      __syncthreads();
      if ((tid & 63) == 0) sRed[tid >> 6] = lsum;
      __syncthreads();
      const float rS = 1.0f / (sRed[0] + sRed[1] + sRed[2] + sRed[3]);
      #pragma unroll
      for (int rep = 0; rep < 2; ++rep) {
        int tp = tid + rep * 256;
        if (tp < TT) {
          float a = sAttn[tp] * rS;
          sAttn[tp] = a;
          if (rb == 0) stx(out, (size_t)PLOT_OFF + (size_t)t * TT + tp, a, isf);  // attn_plot
        }
      }
      __syncthreads();
      {
        // context = attn @ enc_value ; threads split T into two halves
        const int d = tid & 127, half = tid >> 7;
        float acc = 0.0f;
        if (isf) {
          const float* vc = (const float*)enc_value + ((size_t)rb * TT + half * 200) * KVD + d;
          for (int tp2 = 0; tp2 < 200; ++tp2) acc += sAttn[half * 200 + tp2] * vc[(size_t)tp2 * KVD];
        } else {
          const ushort_t* vc = (const ushort_t*)enc_value + ((size_t)rb * TT + half * 200) * KVD + d;
          for (int tp2 = 0; tp2 < 200; ++tp2) acc += sAttn[half * 200 + tp2] * bf2f(vc[(size_t)tp2 * KVD]);
        }
        if (half == 1) sGex[0][d] = acc;
        __syncthreads();
        if (half == 0) xT1[(256 + d) * BB + rb] = acc + sGex[0][d];
      }
    }
    grid_barrier(flags, gen, ++target);
  }
}

extern "C" void kernel_launch(void* const* d_in, const int* in_sizes, int n_in,
                              void* d_out, int out_size, void* d_ws, size_t ws_size,
                              hipStream_t stream) {
  const void* enc_key   = d_in[0];
  const void* enc_value = d_in[1];
  const int*  enc_len   = (const int*)d_in[2];
  const int*  y         = (const int*)d_in[3];
  const void* emb       = d_in[4];
  const void* w_ih1     = d_in[5];
  const void* w_hh1     = d_in[6];
  const void* b_ih1     = d_in[7];
  const void* b_hh1     = d_in[8];
  const void* w_ih2     = d_in[9];
  const void* w_hh2     = d_in[10];
  const void* b_ih2     = d_in[11];
  const void* b_hh2     = d_in[12];
  const void* w_out     = d_in[13];
  const void* b_out     = d_in[14];
  float* ws = (float*)d_ws;

  // 1) detect fp32 vs bf16 (writes isf flag into ws)
  probe_kernel<<<dim3(1), dim3(64), 0, stream>>>(w_out, ws);
  // 2) zero state/barrier region, seed <sos> embedding (reads isf)
  init_kernel<<<dim3((XT_SZ + H2_SZ + NBLK + 1 + NTHR - 1) / NTHR), dim3(NTHR), 0, stream>>>(emb, ws);
  // 3) persistent decode
  decoder_kernel<<<dim3(NBLK), dim3(NTHR), 0, stream>>>(
      enc_key, enc_value, enc_len, y, emb,
      w_ih1, w_hh1, b_ih1, b_hh1,
      w_ih2, w_hh2, b_ih2, b_hh2,
      w_out, b_out, d_out, ws);
}

// Round 6
// 34879.221 us; speedup vs baseline: 7.3431x; 1.4430x over previous
//
#include <hip/hip_runtime.h>
#include <hip/hip_bf16.h>

// Problem constants
#define BB   128   // batch
#define TT   400   // encoder length
#define KVD  128   // key/value dim (= layer2 hidden)
#define VV   1024  // vocab
#define EE   256   // embed dim
#define HH   512   // layer1 hidden
#define LL   300   // decode length
#define D1   896   // E + KV + H (layer1 input incl. recurrent)
#define NBLK 256
#define NTHR 256

// workspace layout (float units) — activations are BATCH-MAJOR: xT[b][k]
#define XT_SZ   (D1 * BB)             // 114688 floats per parity buffer
#define XT_OFF  0                     // 2 buffers
#define H2_SZ   (KVD * BB)            // 16384 floats per parity buffer
#define H2_OFF  (2 * XT_SZ)           // 229376
#define FLAG_OFF (H2_OFF + 2 * H2_SZ) // unsigned flags[256] + gen + isf
#define PLOT_OFF (BB * LL * VV)       // 39321600 (attn_plot offset in out)

typedef unsigned short ushort_t;

__device__ __forceinline__ float bf2f(ushort_t u) {
  return __uint_as_float(((unsigned)u) << 16);
}
__device__ __forceinline__ ushort_t f2bf(float f) {
  unsigned u = __float_as_uint(f);
  return (ushort_t)((u + 0x7FFFu + ((u >> 16) & 1u)) >> 16);  // RNE
}
__device__ __forceinline__ float sigm(float x) { return 1.0f / (1.0f + expf(-x)); }

// dtype-agnostic element load/store (isf: buffer is fp32, else bf16)
__device__ __forceinline__ float ldx(const void* p, size_t i, bool isf) {
  return isf ? ((const float*)p)[i] : bf2f(((const ushort_t*)p)[i]);
}
__device__ __forceinline__ void stx(void* p, size_t i, float v, bool isf) {
  if (isf) ((float*)p)[i] = v; else ((ushort_t*)p)[i] = f2bf(v);
}

// ---------------------------------------------------------------------------
// probe: decide whether float tensors are fp32 or bf16.
// ---------------------------------------------------------------------------
__global__ void probe_kernel(const void* __restrict__ w_out, float* __restrict__ ws) {
  if (blockIdx.x == 0 && threadIdx.x == 0) {
    const ushort_t* p = (const ushort_t*)w_out;
    int bad = 0;
    for (int i = 0; i < 512; ++i) {
      float v = bf2f(p[i]);
      if (!(fabsf(v) < 0.5f)) bad++;   // counts NaN/inf too
    }
    unsigned* flags = (unsigned*)(ws + FLAG_OFF);
    flags[NBLK + 1] = (bad > 0) ? 1u : 0u;
  }
}

// ---------------------------------------------------------------------------
// init: zero parity-0 state, seed <sos> embedding (batch-major), zero flags
// ---------------------------------------------------------------------------
__global__ void __launch_bounds__(NTHR) init_kernel(const void* __restrict__ emb,
                                                    float* __restrict__ ws) {
  unsigned* flags = (unsigned*)(ws + FLAG_OFF);
  const bool isf = flags[NBLK + 1] != 0;
  int idx = blockIdx.x * NTHR + threadIdx.x;
  if (idx < XT_SZ) {
    int k = idx % D1;  // xT[b][k] batch-major: k = idx % D1
    ws[XT_OFF + idx] = (k < EE) ? ldx(emb, EE + k, isf) : 0.0f;  // SOS token = 1
  }
  int j = idx - XT_SZ;
  if (j >= 0 && j < H2_SZ) ws[H2_OFF + j] = 0.0f;
  int f = idx - (XT_SZ + H2_SZ);
  if (f >= 0 && f < NBLK + 1) flags[f] = 0u;   // flags[257] (isf) preserved
}

// ---------------------------------------------------------------------------
// grid barrier — cache-maintenance ONCE PER BLOCK (tid 0), not per wave.
// (round-3 verified: 75ms -> 31.8ms vs per-wave fences. Do not touch.)
// ---------------------------------------------------------------------------
__device__ __forceinline__ void grid_barrier(unsigned* flags, unsigned* gen, unsigned target) {
  __syncthreads();   // all waves' global stores drained to L2
  const int tid = threadIdx.x;
  if (blockIdx.x == 0) {
    if (tid > 0) {
      long spin = 0;
      while (__hip_atomic_load(&flags[tid], __ATOMIC_RELAXED, __HIP_MEMORY_SCOPE_AGENT) < target) {
        __builtin_amdgcn_s_sleep(2);
        if (++spin > (1L << 24)) break;  // bail-out: never expected (co-resident)
      }
    }
    __syncthreads();
    if (tid == 0) {
      __threadfence();  // release (flush block0 data) + acquire (see others' data)
      __hip_atomic_store(gen, target, __ATOMIC_RELEASE, __HIP_MEMORY_SCOPE_AGENT);
    }
    __syncthreads();
  } else {
    if (tid == 0) {
      __threadfence();  // release: publish this block's phase output
      __hip_atomic_store(&flags[blockIdx.x], target, __ATOMIC_RELEASE, __HIP_MEMORY_SCOPE_AGENT);
      long spin = 0;
      while (__hip_atomic_load(gen, __ATOMIC_RELAXED, __HIP_MEMORY_SCOPE_AGENT) < target) {
        __builtin_amdgcn_s_sleep(2);
        if (++spin > (1L << 24)) break;
      }
      __threadfence();  // acquire: invalidate stale L1/L2 before block reads
    }
    __syncthreads();
  }
}

// ---------------------------------------------------------------------------
// persistent decoder — BATCH-MAJOR activations:
// each GEMV thread reads its own contiguous column as float4 (224 loads vs
// 896 scalar), so a 128B line serves 8 consecutive loads -> ~8x fewer long
// misses. Two independent K-streams per loop keep >=2 misses in flight.
// ---------------------------------------------------------------------------
__global__ void __launch_bounds__(NTHR) decoder_kernel(
    const void* __restrict__ enc_key,
    const void* __restrict__ enc_value,
    const int*  __restrict__ enc_len,
    const int*  __restrict__ y,
    const void* __restrict__ emb,
    const void* __restrict__ w_ih1, const void* __restrict__ w_hh1,
    const void* __restrict__ b_ih1, const void* __restrict__ b_hh1,
    const void* __restrict__ w_ih2, const void* __restrict__ w_hh2,
    const void* __restrict__ b_ih2, const void* __restrict__ b_hh2,
    const void* __restrict__ w_out, const void* __restrict__ b_out,
    void* __restrict__ out, float* __restrict__ ws)
{
  // persistent weight slices (fp32, loaded once; reads are wave-uniform broadcasts)
  __shared__ float sW1[8][D1];      // block w owns hu=2w,2w+1: rows 4h+g  (28.7 KB)
  __shared__ float sW2[4][640];     // blocks<128 own layer2 hidden w      (10.2 KB)
  __shared__ float sWo[4][256];     // block w owns vocab rows 4w..4w+3    (4 KB)
  __shared__ float sB1[8];
  __shared__ float sB2[4];
  __shared__ float sBo[4];
  __shared__ float sRed[4];
  __shared__ float sAttn[TT];
  __shared__ float sH2[KVD];
  __shared__ float sGex[2][BB];

  const int tid = threadIdx.x;
  const int w   = blockIdx.x;
  unsigned* flags = (unsigned*)(ws + FLAG_OFF);
  unsigned* gen   = flags + NBLK;
  const bool isf  = flags[NBLK + 1] != 0;   // written by probe_kernel

  // ---- one-time LDS weight staging (-> fp32) ----
  for (int i = tid; i < 8 * D1; i += NTHR) {
    int r = i / D1, k = i - r * D1;        // r = 4h+g
    int g = r & 3, h = r >> 2;
    int R = g * HH + 2 * w + h;            // global gate row in [0,2048)
    sW1[r][k] = (k < EE + KVD) ? ldx(w_ih1, (size_t)R * (EE + KVD) + k, isf)
                               : ldx(w_hh1, (size_t)R * HH + (k - (EE + KVD)), isf);
  }
  if (tid < 8) {
    int R = (tid & 3) * HH + 2 * w + (tid >> 2);
    sB1[tid] = ldx(b_ih1, R, isf) + ldx(b_hh1, R, isf);
  }
  if (w < BB) {
    for (int i = tid; i < 4 * 640; i += NTHR) {
      int g = i / 640, k = i - g * 640;
      int R = g * KVD + w;                 // global gate row in [0,512)
      sW2[g][k] = (k < HH) ? ldx(w_ih2, (size_t)R * HH + k, isf)
                           : ldx(w_hh2, (size_t)R * KVD + (k - HH), isf);
    }
    if (tid < 4) {
      int R = tid * KVD + w;
      sB2[tid] = ldx(b_ih2, R, isf) + ldx(b_hh2, R, isf);
    }
  }
  for (int i = tid; i < 4 * 256; i += NTHR) {
    int r = i >> 8, d = i & 255;
    sWo[r][d] = ldx(w_out, (size_t)(4 * w + r) * 256 + d, isf);
  }
  if (tid < 4) sBo[tid] = ldx(b_out, 4 * w + tid, isf);
  __syncthreads();

  const int b  = tid & 127;   // batch column
  const int hi = tid >> 7;    // half: 0/1
  float c1 = 0.0f;            // c1[hu=2w+hi][b] lives here across all steps
  float c2 = 0.0f;            // (w<128, hi==0): c2[w][b]

  unsigned target = 0;

  for (int t = 0; t <= LL; ++t) {
    const int p0 = t & 1;
    float* xT0  = ws + XT_OFF + p0 * XT_SZ;
    float* xT1  = ws + XT_OFF + (p0 ^ 1) * XT_SZ;
    float* h2T0 = ws + H2_OFF + p0 * H2_SZ;
    float* h2T1 = ws + H2_OFF + (p0 ^ 1) * H2_SZ;

    // ================= Phase A =================
    if (t > 0) {
      // output GEMM for step t-1: logits = [h2(128) | context(128)] @ w_out^T
      // two natural streams: h2 rows (A) and context rows (B)
      float a0 = sBo[2 * hi], a1 = sBo[2 * hi + 1];
      float e0 = 0.0f, e1 = 0.0f;
      const float4* r0 = (const float4*)&sWo[2 * hi][0];
      const float4* r1 = (const float4*)&sWo[2 * hi + 1][0];
      const float4* hp4 = (const float4*)(h2T0 + (size_t)b * KVD);
      const float4* cp4 = (const float4*)(xT0 + (size_t)b * D1 + 256);
      #pragma unroll 2
      for (int q = 0; q < 32; ++q) {
        float4 xA = hp4[q], xB = cp4[q];
        float4 uA0 = r0[q], uA1 = r1[q];
        float4 uB0 = r0[32 + q], uB1 = r1[32 + q];
        a0 += uA0.x * xA.x + uA0.y * xA.y + uA0.z * xA.z + uA0.w * xA.w;
        a1 += uA1.x * xA.x + uA1.y * xA.y + uA1.z * xA.z + uA1.w * xA.w;
        e0 += uB0.x * xB.x + uB0.y * xB.y + uB0.z * xB.z + uB0.w * xB.w;
        e1 += uB1.x * xB.x + uB1.y * xB.y + uB1.z * xB.z + uB1.w * xB.w;
      }
      a0 += e0; a1 += e1;
      int v = 4 * w + 2 * hi;
      size_t oidx = (size_t)b * (LL * VV) + (size_t)(t - 1) * VV + v;
      stx(out, oidx, a0, isf);
      stx(out, oidx + 1, a1, isf);
    }
    if (t == LL) break;                                   // final epilogue done

    {
      // GEMM1 + LSTM1 for step t: x = xT0[b][0..896], contiguous per thread.
      // two K-streams (k and k+448) keep 2+ line-misses in flight.
      const int hu = 2 * w + hi;
      float a0 = sB1[4 * hi + 0], a1 = sB1[4 * hi + 1];
      float a2 = sB1[4 * hi + 2], a3 = sB1[4 * hi + 3];
      float e0 = 0.0f, e1 = 0.0f, e2 = 0.0f, e3 = 0.0f;
      const float4* q0 = (const float4*)&sW1[4 * hi + 0][0];
      const float4* q1 = (const float4*)&sW1[4 * hi + 1][0];
      const float4* q2 = (const float4*)&sW1[4 * hi + 2][0];
      const float4* q3 = (const float4*)&sW1[4 * hi + 3][0];
      const float4* xp4 = (const float4*)(xT0 + (size_t)b * D1);
      #pragma unroll 2
      for (int q = 0; q < 112; ++q) {
        float4 xA = xp4[q], xB = xp4[112 + q];
        float4 uA0 = q0[q], uA1 = q1[q], uA2 = q2[q], uA3 = q3[q];
        float4 uB0 = q0[112 + q], uB1 = q1[112 + q], uB2 = q2[112 + q], uB3 = q3[112 + q];
        a0 += uA0.x * xA.x + uA0.y * xA.y + uA0.z * xA.z + uA0.w * xA.w;
        a1 += uA1.x * xA.x + uA1.y * xA.y + uA1.z * xA.z + uA1.w * xA.w;
        a2 += uA2.x * xA.x + uA2.y * xA.y + uA2.z * xA.z + uA2.w * xA.w;
        a3 += uA3.x * xA.x + uA3.y * xA.y + uA3.z * xA.z + uA3.w * xA.w;
        e0 += uB0.x * xB.x + uB0.y * xB.y + uB0.z * xB.z + uB0.w * xB.w;
        e1 += uB1.x * xB.x + uB1.y * xB.y + uB1.z * xB.z + uB1.w * xB.w;
        e2 += uB2.x * xB.x + uB2.y * xB.y + uB2.z * xB.z + uB2.w * xB.w;
        e3 += uB3.x * xB.x + uB3.y * xB.y + uB3.z * xB.z + uB3.w * xB.w;
      }
      a0 += e0; a1 += e1; a2 += e2; a3 += e3;
      float ig = sigm(a0), fg = sigm(a1), gg = tanhf(a2), og = sigm(a3);
      c1 = fg * c1 + ig * gg;
      float h1v = og * tanhf(c1);
      xT1[(size_t)b * D1 + 384 + hu] = h1v;
    }
    grid_barrier(flags, gen, ++target);

    // ================= Phase B =================
    if (w < BB) {
      // GEMM2 + LSTM2: gates2 = [h1(512) | h2(128)] @ W2^T
      // h1 split into two 256-wide streams; h2 tail separate.
      float a0 = sB2[2 * hi], a1 = sB2[2 * hi + 1];
      float e0 = 0.0f, e1 = 0.0f;
      const float4* r0 = (const float4*)&sW2[2 * hi][0];
      const float4* r1 = (const float4*)&sW2[2 * hi + 1][0];
      const float4* xp4 = (const float4*)(xT1 + (size_t)b * D1 + 384);  // h1(t)
      #pragma unroll 2
      for (int q = 0; q < 64; ++q) {
        float4 xA = xp4[q], xB = xp4[64 + q];
        float4 uA0 = r0[q], uA1 = r1[q];
        float4 uB0 = r0[64 + q], uB1 = r1[64 + q];
        a0 += uA0.x * xA.x + uA0.y * xA.y + uA0.z * xA.z + uA0.w * xA.w;
        a1 += uA1.x * xA.x + uA1.y * xA.y + uA1.z * xA.z + uA1.w * xA.w;
        e0 += uB0.x * xB.x + uB0.y * xB.y + uB0.z * xB.z + uB0.w * xB.w;
        e1 += uB1.x * xB.x + uB1.y * xB.y + uB1.z * xB.z + uB1.w * xB.w;
      }
      a0 += e0; a1 += e1;
      const float4* hp4 = (const float4*)(h2T0 + (size_t)b * KVD);      // h2(t-1)
      #pragma unroll 4
      for (int q = 0; q < 32; ++q) {
        float4 x = hp4[q];
        float4 u0 = r0[128 + q], u1 = r1[128 + q];
        a0 += u0.x * x.x + u0.y * x.y + u0.z * x.z + u0.w * x.w;
        a1 += u1.x * x.x + u1.y * x.y + u1.z * x.z + u1.w * x.w;
      }
      if (hi == 1) { sGex[0][b] = tanhf(a0); sGex[1][b] = sigm(a1); }  // g, o
      __syncthreads();
      if (hi == 0) {                                                   // i, f
        c2 = sigm(a1) * c2 + sigm(a0) * sGex[0][b];
        float h2v = sGex[1][b] * tanhf(c2);
        h2T1[(size_t)b * KVD + w] = h2v;
      }
    } else {
      // embedding gather for step t+1 (teacher forcing: token y[:, t])
      // batch-major write: coalesced across tid
      int j = w - BB;
      int tok = y[j * LL + t];
      xT1[(size_t)j * D1 + tid] = ldx(emb, (size_t)tok * EE + tid, isf);  // tid in [0,256)=E
    }
    grid_barrier(flags, gen, ++target);

    // ================= Phase C =================
    if (w < BB) {
      const int rb = w;                                  // batch row pinned to block
      if (tid < KVD) sH2[tid] = h2T1[(size_t)rb * KVD + tid];   // coalesced row gather
      __syncthreads();
      const int len = enc_len[rb];
      float lmax = -3.0e38f;
      #pragma unroll
      for (int rep = 0; rep < 2; ++rep) {
        int tp = tid + rep * 256;
        float e = -3.0e38f;
        if (tp < TT) {
          float acc = 0.0f;
          if (isf) {
            const float4* kr = (const float4*)((const float*)enc_key + ((size_t)rb * TT + tp) * KVD);
            #pragma unroll 8
            for (int q = 0; q < 32; ++q) {
              float4 u = kr[q];
              acc += u.x * sH2[4 * q + 0] + u.y * sH2[4 * q + 1]
                   + u.z * sH2[4 * q + 2] + u.w * sH2[4 * q + 3];
            }
          } else {
            const ushort4* kr = (const ushort4*)((const ushort_t*)enc_key + ((size_t)rb * TT + tp) * KVD);
            #pragma unroll 8
            for (int q = 0; q < 32; ++q) {
              ushort4 u = kr[q];
              acc += bf2f(u.x) * sH2[4 * q + 0] + bf2f(u.y) * sH2[4 * q + 1]
                   + bf2f(u.z) * sH2[4 * q + 2] + bf2f(u.w) * sH2[4 * q + 3];
            }
          }
          e = (tp < len) ? acc : -1e9f;
          sAttn[tp] = e;
        }
        lmax = fmaxf(lmax, e);
      }
      for (int off = 32; off > 0; off >>= 1) lmax = fmaxf(lmax, __shfl_down(lmax, off, 64));
      if ((tid & 63) == 0) sRed[tid >> 6] = lmax;
      __syncthreads();
      const float m = fmaxf(fmaxf(sRed[0], sRed[1]), fmaxf(sRed[2], sRed[3]));
      float lsum = 0.0f;
      #pragma unroll
      for (int rep = 0; rep < 2; ++rep) {
        int tp = tid + rep * 256;
        if (tp < TT) { float a = expf(sAttn[tp] - m); sAttn[tp] = a; lsum += a; }
      }
      for (int off = 32; off > 0; off >>= 1) lsum += __shfl_down(lsum, off, 64);
      __syncthreads();
      if ((tid & 63) == 0) sRed[tid >> 6] = lsum;
      __syncthreads();
      const float rS = 1.0f / (sRed[0] + sRed[1] + sRed[2] + sRed[3]);
      #pragma unroll
      for (int rep = 0; rep < 2; ++rep) {
        int tp = tid + rep * 256;
        if (tp < TT) {
          float a = sAttn[tp] * rS;
          sAttn[tp] = a;
          if (rb == 0) stx(out, (size_t)PLOT_OFF + (size_t)t * TT + tp, a, isf);  // attn_plot
        }
      }
      __syncthreads();
      {
        // context = attn @ enc_value ; two T-streams (tp, tp+100) per half
        const int d = tid & 127, half = tid >> 7;
        const int tb = half * 200;
        float accA = 0.0f, accB = 0.0f;
        if (isf) {
          const float* vcA = (const float*)enc_value + ((size_t)rb * TT + tb) * KVD + d;
          const float* vcB = vcA + (size_t)100 * KVD;
          #pragma unroll 4
          for (int tp2 = 0; tp2 < 100; ++tp2) {
            accA += sAttn[tb + tp2] * vcA[(size_t)tp2 * KVD];
            accB += sAttn[tb + 100 + tp2] * vcB[(size_t)tp2 * KVD];
          }
        } else {
          const ushort_t* vcA = (const ushort_t*)enc_value + ((size_t)rb * TT + tb) * KVD + d;
          const ushort_t* vcB = vcA + (size_t)100 * KVD;
          #pragma unroll 4
          for (int tp2 = 0; tp2 < 100; ++tp2) {
            accA += sAttn[tb + tp2] * bf2f(vcA[(size_t)tp2 * KVD]);
            accB += sAttn[tb + 100 + tp2] * bf2f(vcB[(size_t)tp2 * KVD]);
          }
        }
        float acc = accA + accB;
        if (half == 1) sGex[0][d] = acc;
        __syncthreads();
        if (half == 0) xT1[(size_t)rb * D1 + 256 + d] = acc + sGex[0][d];  // coalesced
      }
    }
    grid_barrier(flags, gen, ++target);
  }
}

extern "C" void kernel_launch(void* const* d_in, const int* in_sizes, int n_in,
                              void* d_out, int out_size, void* d_ws, size_t ws_size,
                              hipStream_t stream) {
  const void* enc_key   = d_in[0];
  const void* enc_value = d_in[1];
  const int*  enc_len   = (const int*)d_in[2];
  const int*  y         = (const int*)d_in[3];
  const void* emb       = d_in[4];
  const void* w_ih1     = d_in[5];
  const void* w_hh1     = d_in[6];
  const void* b_ih1     = d_in[7];
  const void* b_hh1     = d_in[8];
  const void* w_ih2     = d_in[9];
  const void* w_hh2     = d_in[10];
  const void* b_ih2     = d_in[11];
  const void* b_hh2     = d_in[12];
  const void* w_out     = d_in[13];
  const void* b_out     = d_in[14];
  float* ws = (float*)d_ws;

  // 1) detect fp32 vs bf16 (writes isf flag into ws)
  probe_kernel<<<dim3(1), dim3(64), 0, stream>>>(w_out, ws);
  // 2) zero state/barrier region, seed <sos> embedding (reads isf)
  init_kernel<<<dim3((XT_SZ + H2_SZ + NBLK + 1 + NTHR - 1) / NTHR), dim3(NTHR), 0, stream>>>(emb, ws);
  // 3) persistent decode
  decoder_kernel<<<dim3(NBLK), dim3(NTHR), 0, stream>>>(
      enc_key, enc_value, enc_len, y, emb,
      w_ih1, w_hh1, b_ih1, b_hh1,
      w_ih2, w_hh2, b_ih2, b_hh2,
      w_out, b_out, d_out, ws);
}